// Round 4
// baseline (85.670 us; speedup 1.0000x reference)
//
#include <hip/hip_runtime.h>
#include <math.h>

#define N_NODES  32
#define N_HEADS  4
#define HEAD_DIM 64
#define CDIM     256           // N_HEADS * HEAD_DIM == channels
#define HWPIX    9216          // 96*96
#define ROWF4    2304          // HWPIX/4 float4 per (n,c) row
#define HALF_F4  1152          // float4 per half row (18 per lane)
#define E_BASE   512
#define E_TOT    544           // + 32 self loops
#define NEG_SLOPE 0.2f
#define XS       257           // LDS stride for x tile (conflict-free)
#define POOL_BLK 4096          // 4 waves/block, 2 waves per row

// ---------------------------------------------------------------------------
// Kernel 1: spatial mean pool (partial sums) + hidden prep block.
// Waves 0..16383: half-row each (18 float4/lane), partials -> xpart[2][8192].
// Block POOL_BLK (the +1 block): Wa_src/Wa_dst = W . a_src / W . a_dst,
// fully hidden under the pool's ~45 us memory shadow.
// ---------------------------------------------------------------------------
__global__ __launch_bounds__(256, 8) void pool_kernel(const float* __restrict__ roi,
                                                      const float* __restrict__ W,
                                                      const float* __restrict__ a_src,
                                                      const float* __restrict__ a_dst,
                                                      float* __restrict__ xpart,
                                                      float* __restrict__ Wa_s,
                                                      float* __restrict__ Wa_d) {
    if (blockIdx.x == POOL_BLK) {                     // prep block (tiny)
        const int c = threadIdx.x;                    // 0..255
#pragma unroll
        for (int hd = 0; hd < N_HEADS; ++hd) {
            float as = 0.f, ad = 0.f;
#pragma unroll 8
            for (int f = 0; f < HEAD_DIM; ++f) {
                const float w = W[c * CDIM + hd * HEAD_DIM + f];
                as += w * a_src[hd * HEAD_DIM + f];
                ad += w * a_dst[hd * HEAD_DIM + f];
            }
            Wa_s[c * N_HEADS + hd] = as;
            Wa_d[c * N_HEADS + hd] = ad;
        }
        return;
    }

    const int wave = threadIdx.x >> 6, lane = threadIdx.x & 63;
    const int gw   = blockIdx.x * 4 + wave;           // 0..16383
    const int row  = gw >> 1, half = gw & 1;          // row 0..8191
    const float4* p = reinterpret_cast<const float4*>(roi)
                    + (size_t)row * ROWF4 + half * HALF_F4;

    float s = 0.f;
#pragma unroll
    for (int ch = 0; ch < 2; ++ch) {                  // 2 chunks x 9 float4
        float4 v[9];
#pragma unroll
        for (int j = 0; j < 9; ++j) v[j] = p[lane + (ch * 9 + j) * 64];
#pragma unroll
        for (int j = 0; j < 9; ++j) s += (v[j].x + v[j].y) + (v[j].z + v[j].w);
    }
#pragma unroll
    for (int off = 32; off; off >>= 1) s += __shfl_down(s, off);
    if (lane == 0) xpart[half * 8192 + row] = s;
}

// ---------------------------------------------------------------------------
// Kernel 2: full GAT + classifier. 32 blocks, one per DST node.
// x staged in LDS (stride 257); alphas from precomputed Wa_src/Wa_dst;
// aggregation via the linearity swap: out[t] = sum_c W[c,t] * y[hd(t),c],
// y[hd,c] = sum_s M[s,hd] * x[s,c].  ~512 MACs/thread total.
// ---------------------------------------------------------------------------
__global__ __launch_bounds__(256) void gat_kernel(const int* __restrict__ edge_index,
                                                  const float* __restrict__ xpart,
                                                  const float* __restrict__ Wa_s,
                                                  const float* __restrict__ Wa_d,
                                                  const float* __restrict__ W,
                                                  const float* __restrict__ gat_bias,
                                                  const float* __restrict__ cls_W,
                                                  const float* __restrict__ cls_b,
                                                  float* __restrict__ out) {
    const int n = blockIdx.x;                         // dst node this block owns
    const int t = threadIdx.x;

    __shared__ float    xs[N_NODES * XS];             // x tile, stride 257
    __shared__ float    als[N_NODES * N_HEADS];       // alpha_src, all nodes
    __shared__ float    adn[N_HEADS];                 // alpha_dst, own node
    __shared__ unsigned msegu[N_HEADS];
    __shared__ float    dseg[N_HEADS];
    __shared__ float    M[N_NODES * N_HEADS];         // attention row [s][hd]
    __shared__ float    y[N_HEADS * CDIM];
    __shared__ float    sv[CDIM];
    __shared__ float    red[8][32];

    // stage x = (xpart0 + xpart1) / 9216 into LDS (8 float4 pairs / thread)
    const float inv = 1.0f / (float)HWPIX;
#pragma unroll
    for (int k = 0; k < 8; ++k) {
        const int i4 = t + k * 256;                   // 0..2047
        const float4 a = ((const float4*)xpart)[i4];
        const float4 b = ((const float4*)(xpart + 8192))[i4];
        const int i = i4 * 4, s = i >> 8, c = i & 255;
        xs[s * XS + c + 0] = (a.x + b.x) * inv;
        xs[s * XS + c + 1] = (a.y + b.y) * inv;
        xs[s * XS + c + 2] = (a.z + b.z) * inv;
        xs[s * XS + c + 3] = (a.w + b.w) * inv;
    }
    if (t < N_HEADS) { msegu[t] = 0u; dseg[t] = 0.f; }
    if (t < N_NODES * N_HEADS) M[t] = 0.f;
    __syncthreads();

    // alphas: als[s,hd] = xs[s,:] . Wa_s[:,hd];  adn[hd] = xs[n,:] . Wa_d[:,hd]
    if (t < 132) {
        if (t < 128) {
            const int s = t >> 2, hd = t & 3;
            const float* xrow = &xs[s * XS];
            float acc = 0.f;
#pragma unroll 8
            for (int c = 0; c < CDIM; ++c) acc += xrow[c] * Wa_s[c * N_HEADS + hd];
            als[t] = acc;
        } else {
            const int hd = t - 128;
            const float* xrow = &xs[n * XS];
            float acc = 0.f;
#pragma unroll 8
            for (int c = 0; c < CDIM; ++c) acc += xrow[c] * Wa_d[c * N_HEADS + hd];
            adn[hd] = acc;
        }
    }
    __syncthreads();

    // pass A: segment max over edges into n (monotone uint atomicMax)
    for (int e = t; e < E_TOT; e += 256) {
        int s0, d;
        if (e < E_BASE) { s0 = edge_index[e]; d = edge_index[E_BASE + e]; }
        else            { s0 = e - E_BASE;    d = s0; }          // self loops
        if (d == n) {
#pragma unroll
            for (int hd = 0; hd < N_HEADS; ++hd) {
                float v = als[s0 * N_HEADS + hd] + adn[hd];
                v = (v >= 0.f) ? v : NEG_SLOPE * v;
                const int iv = __float_as_int(v);
                const unsigned key = (iv < 0) ? ~(unsigned)iv
                                              : ((unsigned)iv | 0x80000000u);
                atomicMax(&msegu[hd], key);
            }
        }
    }
    __syncthreads();

    float mx[N_HEADS];
#pragma unroll
    for (int hd = 0; hd < N_HEADS; ++hd) {
        const unsigned key = msegu[hd];
        const int im = (key & 0x80000000u) ? (int)(key & 0x7fffffffu) : (int)~key;
        mx[hd] = __int_as_float(im);
    }

    // pass B: exp, denominator, unnormalized attention row (dups sum correctly)
    for (int e = t; e < E_TOT; e += 256) {
        int s0, d;
        if (e < E_BASE) { s0 = edge_index[e]; d = edge_index[E_BASE + e]; }
        else            { s0 = e - E_BASE;    d = s0; }
        if (d == n) {
#pragma unroll
            for (int hd = 0; hd < N_HEADS; ++hd) {
                float v = als[s0 * N_HEADS + hd] + adn[hd];
                v = (v >= 0.f) ? v : NEG_SLOPE * v;
                const float ex = expf(v - mx[hd]);
                atomicAdd(&dseg[hd], ex);
                atomicAdd(&M[s0 * N_HEADS + hd], ex);
            }
        }
    }
    __syncthreads();

    if (t < N_NODES * N_HEADS) M[t] /= dseg[t & 3];
    __syncthreads();

    // y[hd,c] = sum_s M[s,hd] * xs[s,c]   (thread: hd=t>>6, c = lane + 64k)
    {
        const int hd = t >> 6, l = t & 63;
        float acc0 = 0.f, acc1 = 0.f, acc2 = 0.f, acc3 = 0.f;
#pragma unroll
        for (int s = 0; s < N_NODES; ++s) {
            const float m = M[s * N_HEADS + hd];      // wave-uniform broadcast
            const float* xrow = &xs[s * XS + l];
            acc0 += m * xrow[0];
            acc1 += m * xrow[64];
            acc2 += m * xrow[128];
            acc3 += m * xrow[192];
        }
        y[hd * CDIM + l]       = acc0;
        y[hd * CDIM + l + 64]  = acc1;
        y[hd * CDIM + l + 128] = acc2;
        y[hd * CDIM + l + 192] = acc3;
    }
    __syncthreads();

    // out_gat[t] = sum_c y[hd(t),c] * W[c,t] + bias; then SiLU
    {
        const int head = t >> 6;
        const float* yrow = &y[head * CDIM];
        float acc = 0.f;
#pragma unroll 8
        for (int c = 0; c < CDIM; ++c) acc += yrow[c] * W[c * CDIM + t];
        const float v = acc + gat_bias[t];
        sv[t] = v / (1.0f + expf(-v));                // SiLU
    }
    __syncthreads();

    // classifier: 8 partial groups x 32 cols (cls_W straight from L2), reduce
    {
        const int j = t & 31, g = t >> 5;
        float a = 0.f;
#pragma unroll
        for (int c0 = 0; c0 < 32; ++c0) {
            const int c = g * 32 + c0;
            a += sv[c] * cls_W[c * 32 + j];           // coalesced, L2-hot
        }
        red[g][j] = a;
    }
    __syncthreads();
    if (t < 32) {
        float s2 = cls_b[t];
#pragma unroll
        for (int g2 = 0; g2 < 8; ++g2) s2 += red[g2][t];
        out[n * 32 + t] = s2;
    }
}

// ---------------------------------------------------------------------------
extern "C" void kernel_launch(void* const* d_in, const int* in_sizes, int n_in,
                              void* d_out, int out_size, void* d_ws, size_t ws_size,
                              hipStream_t stream) {
    const float* roi   = (const float*)d_in[0];
    const int*   eidx  = (const int*)d_in[1];
    const float* W     = (const float*)d_in[2];
    const float* a_src = (const float*)d_in[3];
    const float* a_dst = (const float*)d_in[4];
    const float* gbias = (const float*)d_in[5];
    const float* clsW  = (const float*)d_in[6];
    const float* clsb  = (const float*)d_in[7];
    float* out = (float*)d_out;

    float* xpart = (float*)d_ws;               // [2][8192] floats
    float* Wa_s  = xpart + 2 * 8192;           // [256][4]
    float* Wa_d  = Wa_s + CDIM * N_HEADS;      // [256][4]

    pool_kernel<<<POOL_BLK + 1, 256, 0, stream>>>(roi, W, a_src, a_dst,
                                                  xpart, Wa_s, Wa_d);
    gat_kernel<<<N_NODES, 256, 0, stream>>>(eidx, xpart, Wa_s, Wa_d, W,
                                            gbias, clsW, clsb, out);
}

// Round 5
// 80.837 us; speedup vs baseline: 1.0598x; 1.0598x over previous
//
#include <hip/hip_runtime.h>
#include <math.h>

#define N_NODES  32
#define N_HEADS  4
#define HEAD_DIM 64
#define CDIM     256           // N_HEADS * HEAD_DIM == channels
#define HWPIX    9216          // 96*96
#define ROWF4    2304          // HWPIX/4 float4 per (n,c) row
#define E_BASE   512
#define E_TOT    544           // + 32 self loops
#define NEG_SLOPE 0.2f
#define XS       257           // LDS stride for x tile (conflict-free)

// ---------------------------------------------------------------------------
// Kernel 1: spatial mean pool.  roi [32,256,96,96] -> x [32,256]
// One WAVE per (n,c) row: 64 lanes x 36 float4 (4 chunks x 9). 2048 blocks =
// exactly one co-resident round (8 blocks/CU @ VGPR<=64). No LDS, no barriers.
// This is the R3-measured-best structure, unchanged.
// ---------------------------------------------------------------------------
__global__ __launch_bounds__(256, 8) void pool_kernel(const float* __restrict__ roi,
                                                      float* __restrict__ x) {
    const int wave = threadIdx.x >> 6, lane = threadIdx.x & 63;
    const int row = blockIdx.x * 4 + wave;            // 0..8191  (n*256+c)
    const float4* p = reinterpret_cast<const float4*>(roi) + (size_t)row * ROWF4;

    float s = 0.f;
#pragma unroll
    for (int ch = 0; ch < 4; ++ch) {                  // 4 chunks x 9 float4
        float4 v[9];
#pragma unroll
        for (int j = 0; j < 9; ++j) v[j] = p[lane + (ch * 9 + j) * 64];
#pragma unroll
        for (int j = 0; j < 9; ++j) s += (v[j].x + v[j].y) + (v[j].z + v[j].w);
    }
#pragma unroll
    for (int off = 32; off; off >>= 1) s += __shfl_down(s, off);
    if (lane == 0) x[row] = s * (1.0f / (float)HWPIX);
}

// ---------------------------------------------------------------------------
// Kernel 2: full GAT + classifier. 32 blocks, one per DST node.
// Phase 0 (per block, redundant, L2-amortized): Wa_s/Wa_d = W . a_src/a_dst —
//   thread t reads W row t (1 KB coalesced) once; 512 MACs. No serial tail.
// Then: x staged in LDS (stride 257) -> alphas -> edge softmax -> linearity
// swap aggregation: y[hd,c] = sum_s M[s,hd] x[s,c]; out col t = y[hd].W[:,t].
// ---------------------------------------------------------------------------
__global__ __launch_bounds__(256) void gat_kernel(const int* __restrict__ edge_index,
                                                  const float* __restrict__ x,
                                                  const float* __restrict__ W,
                                                  const float* __restrict__ a_src,
                                                  const float* __restrict__ a_dst,
                                                  const float* __restrict__ gat_bias,
                                                  const float* __restrict__ cls_W,
                                                  const float* __restrict__ cls_b,
                                                  float* __restrict__ out) {
    const int n = blockIdx.x;                         // dst node this block owns
    const int t = threadIdx.x;

    __shared__ float    xs[N_NODES * XS];             // x tile, stride 257
    __shared__ float    was[CDIM * N_HEADS];          // W . a_src
    __shared__ float    wad[CDIM * N_HEADS];          // W . a_dst
    __shared__ float    als[N_NODES * N_HEADS];       // alpha_src, all nodes
    __shared__ float    adn[N_HEADS];                 // alpha_dst, own node
    __shared__ unsigned msegu[N_HEADS];
    __shared__ float    dseg[N_HEADS];
    __shared__ float    M[N_NODES * N_HEADS];         // attention row [s][hd]
    __shared__ float    y[N_HEADS * CDIM];
    __shared__ float    sv[CDIM];
    __shared__ float    red[8][32];

    // stage x into LDS (8 float4 / thread)
#pragma unroll
    for (int k = 0; k < 8; ++k) {
        const int i4 = t + k * 256;                   // 0..2047
        const float4 v = ((const float4*)x)[i4];
        const int i = i4 * 4, s = i >> 8, c = i & 255;
        xs[s * XS + c + 0] = v.x;
        xs[s * XS + c + 1] = v.y;
        xs[s * XS + c + 2] = v.z;
        xs[s * XS + c + 3] = v.w;
    }

    // phase 0: Wa vectors. Thread t owns channel c = t; W row t is 1 KB
    // coalesced; a_src/a_dst float4 loads are wave-uniform broadcasts.
    {
        float accs[N_HEADS] = {0.f, 0.f, 0.f, 0.f};
        float accd[N_HEADS] = {0.f, 0.f, 0.f, 0.f};
        const float4* wr  = (const float4*)(W + t * CDIM);
        const float4* as4 = (const float4*)a_src;
        const float4* ad4 = (const float4*)a_dst;
#pragma unroll 8
        for (int q = 0; q < 64; ++q) {                // q -> head q>>4
            const float4 w = wr[q], av = as4[q], dv = ad4[q];
            const int hd = q >> 4;
            accs[hd] += w.x * av.x + w.y * av.y + w.z * av.z + w.w * av.w;
            accd[hd] += w.x * dv.x + w.y * dv.y + w.z * dv.z + w.w * dv.w;
        }
#pragma unroll
        for (int hd = 0; hd < N_HEADS; ++hd) {
            was[t * N_HEADS + hd] = accs[hd];
            wad[t * N_HEADS + hd] = accd[hd];
        }
    }
    if (t < N_HEADS) { msegu[t] = 0u; dseg[t] = 0.f; }
    if (t < N_NODES * N_HEADS) M[t] = 0.f;
    __syncthreads();

    // alphas: als[s,hd] = xs[s,:] . was[:,hd];  adn[hd] = xs[n,:] . wad[:,hd]
    if (t < 132) {
        if (t < 128) {
            const int s = t >> 2, hd = t & 3;
            const float* xrow = &xs[s * XS];
            float acc = 0.f;
#pragma unroll 8
            for (int c = 0; c < CDIM; ++c) acc += xrow[c] * was[c * N_HEADS + hd];
            als[t] = acc;
        } else {
            const int hd = t - 128;
            const float* xrow = &xs[n * XS];
            float acc = 0.f;
#pragma unroll 8
            for (int c = 0; c < CDIM; ++c) acc += xrow[c] * wad[c * N_HEADS + hd];
            adn[hd] = acc;
        }
    }
    __syncthreads();

    // pass A: segment max over edges into n (monotone uint atomicMax)
    for (int e = t; e < E_TOT; e += 256) {
        int s0, d;
        if (e < E_BASE) { s0 = edge_index[e]; d = edge_index[E_BASE + e]; }
        else            { s0 = e - E_BASE;    d = s0; }          // self loops
        if (d == n) {
#pragma unroll
            for (int hd = 0; hd < N_HEADS; ++hd) {
                float v = als[s0 * N_HEADS + hd] + adn[hd];
                v = (v >= 0.f) ? v : NEG_SLOPE * v;
                const int iv = __float_as_int(v);
                const unsigned key = (iv < 0) ? ~(unsigned)iv
                                              : ((unsigned)iv | 0x80000000u);
                atomicMax(&msegu[hd], key);
            }
        }
    }
    __syncthreads();

    float mx[N_HEADS];
#pragma unroll
    for (int hd = 0; hd < N_HEADS; ++hd) {
        const unsigned key = msegu[hd];
        const int im = (key & 0x80000000u) ? (int)(key & 0x7fffffffu) : (int)~key;
        mx[hd] = __int_as_float(im);
    }

    // pass B: exp, denominator, unnormalized attention row (dups sum correctly)
    for (int e = t; e < E_TOT; e += 256) {
        int s0, d;
        if (e < E_BASE) { s0 = edge_index[e]; d = edge_index[E_BASE + e]; }
        else            { s0 = e - E_BASE;    d = s0; }
        if (d == n) {
#pragma unroll
            for (int hd = 0; hd < N_HEADS; ++hd) {
                float v = als[s0 * N_HEADS + hd] + adn[hd];
                v = (v >= 0.f) ? v : NEG_SLOPE * v;
                const float ex = expf(v - mx[hd]);
                atomicAdd(&dseg[hd], ex);
                atomicAdd(&M[s0 * N_HEADS + hd], ex);
            }
        }
    }
    __syncthreads();

    if (t < N_NODES * N_HEADS) M[t] /= dseg[t & 3];
    __syncthreads();

    // y[hd,c] = sum_s M[s,hd] * xs[s,c]   (thread: hd=t>>6, c = lane + 64k)
    {
        const int hd = t >> 6, l = t & 63;
        float acc0 = 0.f, acc1 = 0.f, acc2 = 0.f, acc3 = 0.f;
#pragma unroll
        for (int s = 0; s < N_NODES; ++s) {
            const float m = M[s * N_HEADS + hd];      // wave-uniform broadcast
            const float* xrow = &xs[s * XS + l];
            acc0 += m * xrow[0];
            acc1 += m * xrow[64];
            acc2 += m * xrow[128];
            acc3 += m * xrow[192];
        }
        y[hd * CDIM + l]       = acc0;
        y[hd * CDIM + l + 64]  = acc1;
        y[hd * CDIM + l + 128] = acc2;
        y[hd * CDIM + l + 192] = acc3;
    }
    __syncthreads();

    // out_gat[t] = sum_c y[hd(t),c] * W[c,t] + bias; then SiLU
    {
        const int head = t >> 6;
        const float* yrow = &y[head * CDIM];
        float acc = 0.f;
#pragma unroll 8
        for (int c = 0; c < CDIM; ++c) acc += yrow[c] * W[c * CDIM + t];
        const float v = acc + gat_bias[t];
        sv[t] = v / (1.0f + expf(-v));                // SiLU
    }
    __syncthreads();

    // classifier: 8 partial groups x 32 cols (cls_W from L2), tree reduce
    {
        const int j = t & 31, g = t >> 5;
        float a = 0.f;
#pragma unroll
        for (int c0 = 0; c0 < 32; ++c0) {
            const int c = g * 32 + c0;
            a += sv[c] * cls_W[c * 32 + j];           // coalesced, L2-hot
        }
        red[g][j] = a;
    }
    __syncthreads();
    if (t < 32) {
        float s2 = cls_b[t];
#pragma unroll
        for (int g2 = 0; g2 < 8; ++g2) s2 += red[g2][t];
        out[n * 32 + t] = s2;
    }
}

// ---------------------------------------------------------------------------
extern "C" void kernel_launch(void* const* d_in, const int* in_sizes, int n_in,
                              void* d_out, int out_size, void* d_ws, size_t ws_size,
                              hipStream_t stream) {
    const float* roi   = (const float*)d_in[0];
    const int*   eidx  = (const int*)d_in[1];
    const float* W     = (const float*)d_in[2];
    const float* a_src = (const float*)d_in[3];
    const float* a_dst = (const float*)d_in[4];
    const float* gbias = (const float*)d_in[5];
    const float* clsW  = (const float*)d_in[6];
    const float* clsb  = (const float*)d_in[7];
    float* out = (float*)d_out;

    float* x = (float*)d_ws;                   // [8192] floats

    pool_kernel<<<(N_NODES * CDIM) / 4, 256, 0, stream>>>(roi, x);
    gat_kernel<<<N_NODES, 256, 0, stream>>>(eidx, x, W, a_src, a_dst,
                                            gbias, clsW, clsb, out);
}

// Round 6
// 72.531 us; speedup vs baseline: 1.1812x; 1.1145x over previous
//
#include <hip/hip_runtime.h>
#include <math.h>

#define N_NODES  32
#define N_HEADS  4
#define HEAD_DIM 64
#define CDIM     256           // N_HEADS * HEAD_DIM == channels
#define HWPIX    9216          // 96*96
#define ROWF4    2304          // HWPIX/4 float4 per (n,c) row
#define E_BASE   512
#define E_TOT    544           // + 32 self loops
#define NEG_SLOPE 0.2f
#define XS       257           // LDS stride for x tile (conflict-free)

// ---------------------------------------------------------------------------
// Kernel 1: spatial mean pool.  roi [32,256,96,96] -> x [32,256]
// One WAVE per (n,c) row. v3: explicit 2-buffer software pipeline — load
// chunk k+1 (9 float4) while summing chunk k, so the compiler emits partial
// vmcnt waits instead of full drains. 18 float4 in flight (~90 VGPR) ->
// __launch_bounds__(256,4). 2048 blocks; no LDS, no barriers.
// ---------------------------------------------------------------------------
__global__ __launch_bounds__(256, 4) void pool_kernel(const float* __restrict__ roi,
                                                      float* __restrict__ x) {
    const int wave = threadIdx.x >> 6, lane = threadIdx.x & 63;
    const int row = blockIdx.x * 4 + wave;            // 0..8191  (n*256+c)
    const float4* p = reinterpret_cast<const float4*>(roi) + (size_t)row * ROWF4 + lane;

    float4 A[9], B[9];
    float s = 0.f;

#pragma unroll
    for (int j = 0; j < 9; ++j) A[j] = p[(0 * 9 + j) * 64];   // chunk 0 -> A
#pragma unroll
    for (int j = 0; j < 9; ++j) B[j] = p[(1 * 9 + j) * 64];   // chunk 1 -> B
#pragma unroll
    for (int j = 0; j < 9; ++j) s += (A[j].x + A[j].y) + (A[j].z + A[j].w);
#pragma unroll
    for (int j = 0; j < 9; ++j) A[j] = p[(2 * 9 + j) * 64];   // chunk 2 -> A
#pragma unroll
    for (int j = 0; j < 9; ++j) s += (B[j].x + B[j].y) + (B[j].z + B[j].w);
#pragma unroll
    for (int j = 0; j < 9; ++j) B[j] = p[(3 * 9 + j) * 64];   // chunk 3 -> B
#pragma unroll
    for (int j = 0; j < 9; ++j) s += (A[j].x + A[j].y) + (A[j].z + A[j].w);
#pragma unroll
    for (int j = 0; j < 9; ++j) s += (B[j].x + B[j].y) + (B[j].z + B[j].w);

#pragma unroll
    for (int off = 32; off; off >>= 1) s += __shfl_down(s, off);
    if (lane == 0) x[row] = s * (1.0f / (float)HWPIX);
}

// ---------------------------------------------------------------------------
// Kernel 2: full GAT + classifier. 32 blocks, one per DST node.
// IDENTICAL to R5 (known 80.8 us config) — pool is the only variable.
// ---------------------------------------------------------------------------
__global__ __launch_bounds__(256) void gat_kernel(const int* __restrict__ edge_index,
                                                  const float* __restrict__ x,
                                                  const float* __restrict__ W,
                                                  const float* __restrict__ a_src,
                                                  const float* __restrict__ a_dst,
                                                  const float* __restrict__ gat_bias,
                                                  const float* __restrict__ cls_W,
                                                  const float* __restrict__ cls_b,
                                                  float* __restrict__ out) {
    const int n = blockIdx.x;                         // dst node this block owns
    const int t = threadIdx.x;

    __shared__ float    xs[N_NODES * XS];             // x tile, stride 257
    __shared__ float    was[CDIM * N_HEADS];          // W . a_src
    __shared__ float    wad[CDIM * N_HEADS];          // W . a_dst
    __shared__ float    als[N_NODES * N_HEADS];       // alpha_src, all nodes
    __shared__ float    adn[N_HEADS];                 // alpha_dst, own node
    __shared__ unsigned msegu[N_HEADS];
    __shared__ float    dseg[N_HEADS];
    __shared__ float    M[N_NODES * N_HEADS];         // attention row [s][hd]
    __shared__ float    y[N_HEADS * CDIM];
    __shared__ float    sv[CDIM];
    __shared__ float    red[8][32];

    // stage x into LDS (8 float4 / thread)
#pragma unroll
    for (int k = 0; k < 8; ++k) {
        const int i4 = t + k * 256;                   // 0..2047
        const float4 v = ((const float4*)x)[i4];
        const int i = i4 * 4, s = i >> 8, c = i & 255;
        xs[s * XS + c + 0] = v.x;
        xs[s * XS + c + 1] = v.y;
        xs[s * XS + c + 2] = v.z;
        xs[s * XS + c + 3] = v.w;
    }

    // phase 0: Wa vectors. Thread t owns channel c = t; W row t is 1 KB
    // coalesced; a_src/a_dst float4 loads are wave-uniform broadcasts.
    {
        float accs[N_HEADS] = {0.f, 0.f, 0.f, 0.f};
        float accd[N_HEADS] = {0.f, 0.f, 0.f, 0.f};
        const float4* wr  = (const float4*)(W + t * CDIM);
        const float4* as4 = (const float4*)a_src;
        const float4* ad4 = (const float4*)a_dst;
#pragma unroll 8
        for (int q = 0; q < 64; ++q) {                // q -> head q>>4
            const float4 w = wr[q], av = as4[q], dv = ad4[q];
            const int hd = q >> 4;
            accs[hd] += w.x * av.x + w.y * av.y + w.z * av.z + w.w * av.w;
            accd[hd] += w.x * dv.x + w.y * dv.y + w.z * dv.z + w.w * dv.w;
        }
#pragma unroll
        for (int hd = 0; hd < N_HEADS; ++hd) {
            was[t * N_HEADS + hd] = accs[hd];
            wad[t * N_HEADS + hd] = accd[hd];
        }
    }
    if (t < N_HEADS) { msegu[t] = 0u; dseg[t] = 0.f; }
    if (t < N_NODES * N_HEADS) M[t] = 0.f;
    __syncthreads();

    // alphas: als[s,hd] = xs[s,:] . was[:,hd];  adn[hd] = xs[n,:] . wad[:,hd]
    if (t < 132) {
        if (t < 128) {
            const int s = t >> 2, hd = t & 3;
            const float* xrow = &xs[s * XS];
            float acc = 0.f;
#pragma unroll 8
            for (int c = 0; c < CDIM; ++c) acc += xrow[c] * was[c * N_HEADS + hd];
            als[t] = acc;
        } else {
            const int hd = t - 128;
            const float* xrow = &xs[n * XS];
            float acc = 0.f;
#pragma unroll 8
            for (int c = 0; c < CDIM; ++c) acc += xrow[c] * wad[c * N_HEADS + hd];
            adn[hd] = acc;
        }
    }
    __syncthreads();

    // pass A: segment max over edges into n (monotone uint atomicMax)
    for (int e = t; e < E_TOT; e += 256) {
        int s0, d;
        if (e < E_BASE) { s0 = edge_index[e]; d = edge_index[E_BASE + e]; }
        else            { s0 = e - E_BASE;    d = s0; }          // self loops
        if (d == n) {
#pragma unroll
            for (int hd = 0; hd < N_HEADS; ++hd) {
                float v = als[s0 * N_HEADS + hd] + adn[hd];
                v = (v >= 0.f) ? v : NEG_SLOPE * v;
                const int iv = __float_as_int(v);
                const unsigned key = (iv < 0) ? ~(unsigned)iv
                                              : ((unsigned)iv | 0x80000000u);
                atomicMax(&msegu[hd], key);
            }
        }
    }
    __syncthreads();

    float mx[N_HEADS];
#pragma unroll
    for (int hd = 0; hd < N_HEADS; ++hd) {
        const unsigned key = msegu[hd];
        const int im = (key & 0x80000000u) ? (int)(key & 0x7fffffffu) : (int)~key;
        mx[hd] = __int_as_float(im);
    }

    // pass B: exp, denominator, unnormalized attention row (dups sum correctly)
    for (int e = t; e < E_TOT; e += 256) {
        int s0, d;
        if (e < E_BASE) { s0 = edge_index[e]; d = edge_index[E_BASE + e]; }
        else            { s0 = e - E_BASE;    d = s0; }
        if (d == n) {
#pragma unroll
            for (int hd = 0; hd < N_HEADS; ++hd) {
                float v = als[s0 * N_HEADS + hd] + adn[hd];
                v = (v >= 0.f) ? v : NEG_SLOPE * v;
                const float ex = expf(v - mx[hd]);
                atomicAdd(&dseg[hd], ex);
                atomicAdd(&M[s0 * N_HEADS + hd], ex);
            }
        }
    }
    __syncthreads();

    if (t < N_NODES * N_HEADS) M[t] /= dseg[t & 3];
    __syncthreads();

    // y[hd,c] = sum_s M[s,hd] * xs[s,c]   (thread: hd=t>>6, c = lane + 64k)
    {
        const int hd = t >> 6, l = t & 63;
        float acc0 = 0.f, acc1 = 0.f, acc2 = 0.f, acc3 = 0.f;
#pragma unroll
        for (int s = 0; s < N_NODES; ++s) {
            const float m = M[s * N_HEADS + hd];      // wave-uniform broadcast
            const float* xrow = &xs[s * XS + l];
            acc0 += m * xrow[0];
            acc1 += m * xrow[64];
            acc2 += m * xrow[128];
            acc3 += m * xrow[192];
        }
        y[hd * CDIM + l]       = acc0;
        y[hd * CDIM + l + 64]  = acc1;
        y[hd * CDIM + l + 128] = acc2;
        y[hd * CDIM + l + 192] = acc3;
    }
    __syncthreads();

    // out_gat[t] = sum_c y[hd(t),c] * W[c,t] + bias; then SiLU
    {
        const int head = t >> 6;
        const float* yrow = &y[head * CDIM];
        float acc = 0.f;
#pragma unroll 8
        for (int c = 0; c < CDIM; ++c) acc += yrow[c] * W[c * CDIM + t];
        const float v = acc + gat_bias[t];
        sv[t] = v / (1.0f + expf(-v));                // SiLU
    }
    __syncthreads();

    // classifier: 8 partial groups x 32 cols (cls_W from L2), tree reduce
    {
        const int j = t & 31, g = t >> 5;
        float a = 0.f;
#pragma unroll
        for (int c0 = 0; c0 < 32; ++c0) {
            const int c = g * 32 + c0;
            a += sv[c] * cls_W[c * 32 + j];           // coalesced, L2-hot
        }
        red[g][j] = a;
    }
    __syncthreads();
    if (t < 32) {
        float s2 = cls_b[t];
#pragma unroll
        for (int g2 = 0; g2 < 8; ++g2) s2 += red[g2][t];
        out[n * 32 + t] = s2;
    }
}

// ---------------------------------------------------------------------------
extern "C" void kernel_launch(void* const* d_in, const int* in_sizes, int n_in,
                              void* d_out, int out_size, void* d_ws, size_t ws_size,
                              hipStream_t stream) {
    const float* roi   = (const float*)d_in[0];
    const int*   eidx  = (const int*)d_in[1];
    const float* W     = (const float*)d_in[2];
    const float* a_src = (const float*)d_in[3];
    const float* a_dst = (const float*)d_in[4];
    const float* gbias = (const float*)d_in[5];
    const float* clsW  = (const float*)d_in[6];
    const float* clsb  = (const float*)d_in[7];
    float* out = (float*)d_out;

    float* x = (float*)d_ws;                   // [8192] floats

    pool_kernel<<<(N_NODES * CDIM) / 4, 256, 0, stream>>>(roi, x);
    gat_kernel<<<N_NODES, 256, 0, stream>>>(eidx, x, W, a_src, a_dst,
                                            gbias, clsW, clsb, out);
}

// Round 7
// 72.514 us; speedup vs baseline: 1.1814x; 1.0002x over previous
//
#include <hip/hip_runtime.h>
#include <math.h>

#define N_NODES  32
#define N_HEADS  4
#define HEAD_DIM 64
#define CDIM     256           // N_HEADS * HEAD_DIM == channels
#define HWPIX    9216          // 96*96
#define ROWF4    2304          // HWPIX/4 float4 per (n,c) row
#define E_BASE   512
#define E_TOT    544           // + 32 self loops
#define NEG_SLOPE 0.2f
#define XS       257           // LDS stride for x tile (conflict-free)

// ---------------------------------------------------------------------------
// Kernel 1: spatial mean pool.  roi [32,256,96,96] -> x [32,256]
// One WAVE per (n,c) row. v4: A/B pipeline deepened to 12-float4 chunks
// (3 chunks x 12; peak 24 float4 = 96 data VGPRs, ~116 total < 128 cap).
// 2048 blocks; no LDS, no barriers.
// ---------------------------------------------------------------------------
__global__ __launch_bounds__(256, 4) void pool_kernel(const float* __restrict__ roi,
                                                      float* __restrict__ x) {
    const int wave = threadIdx.x >> 6, lane = threadIdx.x & 63;
    const int row = blockIdx.x * 4 + wave;            // 0..8191  (n*256+c)
    const float4* p = reinterpret_cast<const float4*>(roi) + (size_t)row * ROWF4 + lane;

    float4 A[12], B[12];
    float s = 0.f;

#pragma unroll
    for (int j = 0; j < 12; ++j) A[j] = p[j * 64];              // chunk 0 -> A
#pragma unroll
    for (int j = 0; j < 12; ++j) B[j] = p[(12 + j) * 64];       // chunk 1 -> B
#pragma unroll
    for (int j = 0; j < 12; ++j) s += (A[j].x + A[j].y) + (A[j].z + A[j].w);
#pragma unroll
    for (int j = 0; j < 12; ++j) A[j] = p[(24 + j) * 64];       // chunk 2 -> A
#pragma unroll
    for (int j = 0; j < 12; ++j) s += (B[j].x + B[j].y) + (B[j].z + B[j].w);
#pragma unroll
    for (int j = 0; j < 12; ++j) s += (A[j].x + A[j].y) + (A[j].z + A[j].w);

#pragma unroll
    for (int off = 32; off; off >>= 1) s += __shfl_down(s, off);
    if (lane == 0) x[row] = s * (1.0f / (float)HWPIX);
}

// ---------------------------------------------------------------------------
// Kernel 2: full GAT + classifier. 32 blocks, one per DST node.
// v2 latency fixes: a_src/a_dst staged to LDS (phase 0 becomes W-only load
// stream + uniform ds_read_b128 broadcasts), phase-0 and out_gat W chains
// at unroll 16 (halved latency batches). 1 block/CU -> VGPRs are free.
// ---------------------------------------------------------------------------
__global__ __launch_bounds__(256) void gat_kernel(const int* __restrict__ edge_index,
                                                  const float* __restrict__ x,
                                                  const float* __restrict__ W,
                                                  const float* __restrict__ a_src,
                                                  const float* __restrict__ a_dst,
                                                  const float* __restrict__ gat_bias,
                                                  const float* __restrict__ cls_W,
                                                  const float* __restrict__ cls_b,
                                                  float* __restrict__ out) {
    const int n = blockIdx.x;                         // dst node this block owns
    const int t = threadIdx.x;

    __shared__ float    xs[N_NODES * XS];             // x tile, stride 257
    __shared__ __align__(16) float asl[CDIM];         // a_src flat
    __shared__ __align__(16) float adl[CDIM];         // a_dst flat
    __shared__ float    was[CDIM * N_HEADS];          // W . a_src
    __shared__ float    wad[CDIM * N_HEADS];          // W . a_dst
    __shared__ float    als[N_NODES * N_HEADS];       // alpha_src, all nodes
    __shared__ float    adn[N_HEADS];                 // alpha_dst, own node
    __shared__ unsigned msegu[N_HEADS];
    __shared__ float    dseg[N_HEADS];
    __shared__ float    M[N_NODES * N_HEADS];         // attention row [s][hd]
    __shared__ float    y[N_HEADS * CDIM];
    __shared__ float    sv[CDIM];
    __shared__ float    red[8][32];

    // stage a-vectors; barrier BEFORE issuing the big load streams so the
    // x/W global-load latency still overlaps phase-0 compute.
    asl[t] = a_src[t];
    adl[t] = a_dst[t];
    if (t < N_HEADS) { msegu[t] = 0u; dseg[t] = 0.f; }
    if (t < N_NODES * N_HEADS) M[t] = 0.f;
    __syncthreads();

    // stage x into LDS (8 float4 / thread)
#pragma unroll
    for (int k = 0; k < 8; ++k) {
        const int i4 = t + k * 256;                   // 0..2047
        const float4 v = ((const float4*)x)[i4];
        const int i = i4 * 4, s = i >> 8, c = i & 255;
        xs[s * XS + c + 0] = v.x;
        xs[s * XS + c + 1] = v.y;
        xs[s * XS + c + 2] = v.z;
        xs[s * XS + c + 3] = v.w;
    }

    // phase 0: Wa vectors. Thread t owns channel c = t; W row t is 1 KB
    // coalesced float4 x16-unroll; a-vectors are uniform LDS broadcasts.
    {
        float accs[N_HEADS] = {0.f, 0.f, 0.f, 0.f};
        float accd[N_HEADS] = {0.f, 0.f, 0.f, 0.f};
        const float4* wr  = (const float4*)(W + t * CDIM);
        const float4* as4 = (const float4*)asl;
        const float4* ad4 = (const float4*)adl;
#pragma unroll 16
        for (int q = 0; q < 64; ++q) {                // q -> head q>>4
            const float4 w = wr[q], av = as4[q], dv = ad4[q];
            const int hd = q >> 4;
            accs[hd] += w.x * av.x + w.y * av.y + w.z * av.z + w.w * av.w;
            accd[hd] += w.x * dv.x + w.y * dv.y + w.z * dv.z + w.w * dv.w;
        }
#pragma unroll
        for (int hd = 0; hd < N_HEADS; ++hd) {
            was[t * N_HEADS + hd] = accs[hd];
            wad[t * N_HEADS + hd] = accd[hd];
        }
    }
    __syncthreads();

    // alphas: als[s,hd] = xs[s,:] . was[:,hd];  adn[hd] = xs[n,:] . wad[:,hd]
    if (t < 132) {
        if (t < 128) {
            const int s = t >> 2, hd = t & 3;
            const float* xrow = &xs[s * XS];
            float acc = 0.f;
#pragma unroll 8
            for (int c = 0; c < CDIM; ++c) acc += xrow[c] * was[c * N_HEADS + hd];
            als[t] = acc;
        } else {
            const int hd = t - 128;
            const float* xrow = &xs[n * XS];
            float acc = 0.f;
#pragma unroll 8
            for (int c = 0; c < CDIM; ++c) acc += xrow[c] * wad[c * N_HEADS + hd];
            adn[hd] = acc;
        }
    }
    __syncthreads();

    // pass A: segment max over edges into n (monotone uint atomicMax)
    for (int e = t; e < E_TOT; e += 256) {
        int s0, d;
        if (e < E_BASE) { s0 = edge_index[e]; d = edge_index[E_BASE + e]; }
        else            { s0 = e - E_BASE;    d = s0; }          // self loops
        if (d == n) {
#pragma unroll
            for (int hd = 0; hd < N_HEADS; ++hd) {
                float v = als[s0 * N_HEADS + hd] + adn[hd];
                v = (v >= 0.f) ? v : NEG_SLOPE * v;
                const int iv = __float_as_int(v);
                const unsigned key = (iv < 0) ? ~(unsigned)iv
                                              : ((unsigned)iv | 0x80000000u);
                atomicMax(&msegu[hd], key);
            }
        }
    }
    __syncthreads();

    float mx[N_HEADS];
#pragma unroll
    for (int hd = 0; hd < N_HEADS; ++hd) {
        const unsigned key = msegu[hd];
        const int im = (key & 0x80000000u) ? (int)(key & 0x7fffffffu) : (int)~key;
        mx[hd] = __int_as_float(im);
    }

    // pass B: exp, denominator, unnormalized attention row (dups sum correctly)
    for (int e = t; e < E_TOT; e += 256) {
        int s0, d;
        if (e < E_BASE) { s0 = edge_index[e]; d = edge_index[E_BASE + e]; }
        else            { s0 = e - E_BASE;    d = s0; }
        if (d == n) {
#pragma unroll
            for (int hd = 0; hd < N_HEADS; ++hd) {
                float v = als[s0 * N_HEADS + hd] + adn[hd];
                v = (v >= 0.f) ? v : NEG_SLOPE * v;
                const float ex = expf(v - mx[hd]);
                atomicAdd(&dseg[hd], ex);
                atomicAdd(&M[s0 * N_HEADS + hd], ex);
            }
        }
    }
    __syncthreads();

    if (t < N_NODES * N_HEADS) M[t] /= dseg[t & 3];
    __syncthreads();

    // y[hd,c] = sum_s M[s,hd] * xs[s,c]   (thread: hd=t>>6, c = lane + 64k)
    {
        const int hd = t >> 6, l = t & 63;
        float acc0 = 0.f, acc1 = 0.f, acc2 = 0.f, acc3 = 0.f;
#pragma unroll
        for (int s = 0; s < N_NODES; ++s) {
            const float m = M[s * N_HEADS + hd];      // wave-uniform broadcast
            const float* xrow = &xs[s * XS + l];
            acc0 += m * xrow[0];
            acc1 += m * xrow[64];
            acc2 += m * xrow[128];
            acc3 += m * xrow[192];
        }
        y[hd * CDIM + l]       = acc0;
        y[hd * CDIM + l + 64]  = acc1;
        y[hd * CDIM + l + 128] = acc2;
        y[hd * CDIM + l + 192] = acc3;
    }
    __syncthreads();

    // out_gat[t] = sum_c y[hd(t),c] * W[c,t] + bias; then SiLU
    {
        const int head = t >> 6;
        const float* yrow = &y[head * CDIM];
        float acc = 0.f;
#pragma unroll 16
        for (int c = 0; c < CDIM; ++c) acc += yrow[c] * W[c * CDIM + t];
        const float v = acc + gat_bias[t];
        sv[t] = v / (1.0f + expf(-v));                // SiLU
    }
    __syncthreads();

    // classifier: 8 partial groups x 32 cols (cls_W from L2), tree reduce
    {
        const int j = t & 31, g = t >> 5;
        float a = 0.f;
#pragma unroll
        for (int c0 = 0; c0 < 32; ++c0) {
            const int c = g * 32 + c0;
            a += sv[c] * cls_W[c * 32 + j];           // coalesced, L2-hot
        }
        red[g][j] = a;
    }
    __syncthreads();
    if (t < 32) {
        float s2 = cls_b[t];
#pragma unroll
        for (int g2 = 0; g2 < 8; ++g2) s2 += red[g2][t];
        out[n * 32 + t] = s2;
    }
}

// ---------------------------------------------------------------------------
extern "C" void kernel_launch(void* const* d_in, const int* in_sizes, int n_in,
                              void* d_out, int out_size, void* d_ws, size_t ws_size,
                              hipStream_t stream) {
    const float* roi   = (const float*)d_in[0];
    const int*   eidx  = (const int*)d_in[1];
    const float* W     = (const float*)d_in[2];
    const float* a_src = (const float*)d_in[3];
    const float* a_dst = (const float*)d_in[4];
    const float* gbias = (const float*)d_in[5];
    const float* clsW  = (const float*)d_in[6];
    const float* clsb  = (const float*)d_in[7];
    float* out = (float*)d_out;

    float* x = (float*)d_ws;                   // [8192] floats

    pool_kernel<<<(N_NODES * CDIM) / 4, 256, 0, stream>>>(roi, x);
    gat_kernel<<<N_NODES, 256, 0, stream>>>(eidx, x, W, a_src, a_dst,
                                            gbias, clsW, clsb, out);
}